// Round 1
// baseline (1315.003 us; speedup 1.0000x reference)
//
#include <hip/hip_runtime.h>

// Problem constants (from reference)
#define NN 50000
#define NE 800000
#define HH 64
#define LL 4
#define GG 500
#define CC 10
#define BN_EPS 1e-5f

// ---------------------------------------------------------------------------
// CSR build: histogram of dst, exclusive scan, scatter src ids.
// ---------------------------------------------------------------------------
__global__ __launch_bounds__(256) void k_hist(const int* __restrict__ dst, int* __restrict__ deg) {
    int e = blockIdx.x * 256 + threadIdx.x;
    if (e < NE) atomicAdd(&deg[dst[e]], 1);
}

__global__ __launch_bounds__(1024) void k_scan(const int* __restrict__ deg, int* __restrict__ row_ptr) {
    __shared__ int sums[1024];
    int tid = threadIdx.x;
    const int chunk = (NN + 1023) / 1024;   // 49
    int start = tid * chunk;
    int end = start + chunk;
    if (start > NN) start = NN;
    if (end > NN) end = NN;
    int s = 0;
    for (int i = start; i < end; ++i) s += deg[i];
    sums[tid] = s;
    __syncthreads();
    // Hillis-Steele inclusive scan over the 1024 partials
    for (int off = 1; off < 1024; off <<= 1) {
        int v = 0;
        if (tid >= off) v = sums[tid - off];
        __syncthreads();
        if (tid >= off) sums[tid] += v;
        __syncthreads();
    }
    int run = (tid == 0) ? 0 : sums[tid - 1];
    for (int i = start; i < end; ++i) { row_ptr[i] = run; run += deg[i]; }
    if (tid == 1023) row_ptr[NN] = sums[1023];
}

__global__ __launch_bounds__(256) void k_scatter(const int* __restrict__ src, const int* __restrict__ dst,
                                                 const int* __restrict__ row_ptr, int* __restrict__ cursor,
                                                 int* __restrict__ col) {
    int e = blockIdx.x * 256 + threadIdx.x;
    if (e < NE) {
        int d = dst[e];
        int pos = atomicAdd(&cursor[d], 1);
        col[row_ptr[d] + pos] = src[e];
    }
}

// ---------------------------------------------------------------------------
// One fused GIN layer: wave-per-node.
//   lane c holds feature c. Gather (h_i + sum h_j), GEMM1 via shfl-broadcast,
//   BN1+ReLU, GEMM2 via shfl-broadcast, BN2+ReLU, write h_out, atomic JK-pool.
// ---------------------------------------------------------------------------
__global__ __launch_bounds__(256) void k_layer(
    const float* __restrict__ h_in, float* __restrict__ h_out,
    const int* __restrict__ row_ptr, const int* __restrict__ col,
    const int* __restrict__ batch,
    const float* __restrict__ W1, const float* __restrict__ lb1,
    const float* __restrict__ g1, const float* __restrict__ bb1,
    const float* __restrict__ m1, const float* __restrict__ v1,
    const float* __restrict__ W2, const float* __restrict__ lb2,
    const float* __restrict__ g2, const float* __restrict__ bb2,
    const float* __restrict__ m2, const float* __restrict__ v2,
    float* __restrict__ pooled, int layer)
{
    __shared__ float W1s[64 * 64];
    __shared__ float W2s[64 * 64];
    __shared__ float sc1[64], sh1[64], sc2[64], sh2[64];
    int tid = threadIdx.x;
    for (int i = tid; i < 64 * 64; i += 256) { W1s[i] = W1[i]; W2s[i] = W2[i]; }
    if (tid < 64) {
        // y = relu(scale*dot + shift), shift folds linear bias + BN shift
        float s1 = g1[tid] * rsqrtf(v1[tid] + BN_EPS);
        sc1[tid] = s1;
        sh1[tid] = (lb1[tid] - m1[tid]) * s1 + bb1[tid];
        float s2 = g2[tid] * rsqrtf(v2[tid] + BN_EPS);
        sc2[tid] = s2;
        sh2[tid] = (lb2[tid] - m2[tid]) * s2 + bb2[tid];
    }
    __syncthreads();

    int lane = tid & 63;
    int wave = tid >> 6;
    int wstride = gridDim.x * 4;
    for (int n = blockIdx.x * 4 + wave; n < NN; n += wstride) {
        // GIN aggregation: h_n + sum of incoming neighbors (coalesced 256B rows)
        float acc = h_in[n * 64 + lane];
        int beg = row_ptr[n], fin = row_ptr[n + 1];
        for (int j = beg; j < fin; ++j) {
            int s = col[j];                    // wave-uniform
            acc += h_in[s * 64 + lane];
        }
        // GEMM1: d1[c] = sum_k acc[k] * W1[k][c]
        float d1 = 0.f;
        #pragma unroll
        for (int k = 0; k < 64; ++k)
            d1 = fmaf(__shfl(acc, k), W1s[k * 64 + lane], d1);
        float z1 = fmaxf(fmaf(d1, sc1[lane], sh1[lane]), 0.f);
        // GEMM2
        float d2 = 0.f;
        #pragma unroll
        for (int k = 0; k < 64; ++k)
            d2 = fmaf(__shfl(z1, k), W2s[k * 64 + lane], d2);
        float z2 = fmaxf(fmaf(d2, sc2[lane], sh2[lane]), 0.f);

        h_out[n * 64 + lane] = z2;
        // JK 'cat' + sum-pool readout, fused: pooled[g][layer*64 + c] += z2
        atomicAdd(&pooled[batch[n] * (LL * HH) + layer * HH + lane], z2);
    }
}

// ---------------------------------------------------------------------------
// Final MLP: relu(pooled @ lin1 + b1) @ lin2 + b2. One block per graph.
// ---------------------------------------------------------------------------
__global__ __launch_bounds__(64) void k_mlp(const float* __restrict__ pooled,
                                            const float* __restrict__ w1, const float* __restrict__ b1,
                                            const float* __restrict__ w2, const float* __restrict__ b2,
                                            float* __restrict__ out)
{
    int g = blockIdx.x, c = threadIdx.x;
    __shared__ float hh[64];
    float acc = b1[c];
    const float* p = pooled + g * (LL * HH);
    #pragma unroll 8
    for (int k = 0; k < LL * HH; ++k) acc = fmaf(p[k], w1[k * HH + c], acc);
    hh[c] = fmaxf(acc, 0.f);
    __syncthreads();
    if (c < CC) {
        float o = b2[c];
        #pragma unroll
        for (int k = 0; k < HH; ++k) o = fmaf(hh[k], w2[k * CC + c], o);
        out[g * CC + c] = o;
    }
}

// ---------------------------------------------------------------------------
extern "C" void kernel_launch(void* const* d_in, const int* in_sizes, int n_in,
                              void* d_out, int out_size, void* d_ws, size_t ws_size,
                              hipStream_t stream) {
    const float* x    = (const float*)d_in[0];
    const int*   ei   = (const int*)d_in[1];
    const int*   bat  = (const int*)d_in[2];
    const float* cW1  = (const float*)d_in[3];
    const float* cb1  = (const float*)d_in[4];
    const float* g1   = (const float*)d_in[5];
    const float* bb1  = (const float*)d_in[6];
    const float* m1   = (const float*)d_in[7];
    const float* v1   = (const float*)d_in[8];
    const float* cW2  = (const float*)d_in[9];
    const float* cb2  = (const float*)d_in[10];
    const float* g2   = (const float*)d_in[11];
    const float* bb2  = (const float*)d_in[12];
    const float* m2   = (const float*)d_in[13];
    const float* v2   = (const float*)d_in[14];
    const float* l1W  = (const float*)d_in[15];
    const float* l1b  = (const float*)d_in[16];
    const float* l2W  = (const float*)d_in[17];
    const float* l2b  = (const float*)d_in[18];

    const int* srcp = ei;            // edge_index[0] : source nodes
    const int* dstp = ei + NE;       // edge_index[1] : destination nodes

    char* ws = (char*)d_ws;
    size_t off = 0;
    auto alloc = [&](size_t bytes) -> char* {
        char* p = ws + off;
        off += (bytes + 255) & ~size_t(255);
        return p;
    };
    float* h0      = (float*)alloc((size_t)NN * HH * sizeof(float));
    float* h1      = (float*)alloc((size_t)NN * HH * sizeof(float));
    float* pooled  = (float*)alloc((size_t)GG * LL * HH * sizeof(float));
    int*   row_ptr = (int*)alloc((size_t)(NN + 1) * sizeof(int));
    int*   deg     = (int*)alloc((size_t)NN * sizeof(int));
    int*   cursor  = (int*)alloc((size_t)NN * sizeof(int));
    int*   colx    = (int*)alloc((size_t)NE * sizeof(int));

    hipMemsetAsync(deg, 0, (size_t)NN * sizeof(int), stream);
    hipMemsetAsync(cursor, 0, (size_t)NN * sizeof(int), stream);
    hipMemsetAsync(pooled, 0, (size_t)GG * LL * HH * sizeof(float), stream);

    // CSR build (reused by all 4 layers)
    k_hist<<<(NE + 255) / 256, 256, 0, stream>>>(dstp, deg);
    k_scan<<<1, 1024, 0, stream>>>(deg, row_ptr);
    k_scatter<<<(NE + 255) / 256, 256, 0, stream>>>(srcp, dstp, row_ptr, cursor, colx);

    const float* hin = x;
    float* bufs[2] = { h0, h1 };
    for (int l = 0; l < LL; ++l) {
        float* hout = bufs[l & 1];
        k_layer<<<2048, 256, 0, stream>>>(hin, hout, row_ptr, colx, bat,
            cW1 + (size_t)l * HH * HH, cb1 + l * HH,
            g1 + l * HH, bb1 + l * HH, m1 + l * HH, v1 + l * HH,
            cW2 + (size_t)l * HH * HH, cb2 + l * HH,
            g2 + l * HH, bb2 + l * HH, m2 + l * HH, v2 + l * HH,
            pooled, l);
        hin = hout;
    }

    k_mlp<<<GG, 64, 0, stream>>>(pooled, l1W, l1b, l2W, l2b, (float*)d_out);
}